// Round 3
// baseline (279.056 us; speedup 1.0000x reference)
//
#include <hip/hip_runtime.h>
#include <hip/hip_bf16.h>

// CouplingSplineLayer fused kernel for MI355X (gfx950), round 11.
// R11 = R10's occupancy (32 waves/CU) + R8's weight amortization (128 rows):
//  * 1024-thread blocks, ROWS=128, LDS 66 KB -> 2 blocks/CU x 16 waves
//    = 8 waves/SIMD (same as R10's 4x8, but half the blocks -> half the
//    per-dispatch L2 weight-fragment traffic).
//  * G1 dup-free (wave = m-tile), G2 = (mp:8 m-pairs)x(bh:2 batch-quads),
//    G3 = (nc:4 n-groups)x(bq:4 batch-pairs).
//  * Write-amplification fix (R10's 111 MB WRITE_SIZE vs 36 MB ideal):
//    no separate x2-passthrough; epilogue writes the FULL 64-B out line
//    (spline half + passthrough half) from adjacent stores in one wave.
//  * bias stays folded into the MFMA C-operand.

typedef __bf16 bf16x8 __attribute__((ext_vector_type(8)));
typedef __bf16 bf16x4v __attribute__((ext_vector_type(4)));
typedef float  f32x8 __attribute__((ext_vector_type(8)));
typedef float  f32x4 __attribute__((ext_vector_type(4)));
typedef float  f32x2 __attribute__((ext_vector_type(2)));

#define MFMA16(a,b,c) __builtin_amdgcn_mfma_f32_16x16x32_bf16((a),(b),(c),0,0,0)

// sw layout (bf16 elems) -- identical to R8/R10:
//   W0' : 16x16 A-frags, 1 kb x 16 mt x 512  =  8192
//   W1' : 16x16 A-frags, 8 kb x 16 mt x 512  = 65536
//   Wout': 16x16 A-frags, 8 kb x 12 nt x 512 = 49152 (192 padded cols)
//   bout'[192] floats (*log2e) after SW_TOTAL
#define SW_W1_OFF 8192
#define SW_WO_OFF 73728
#define SW_TOTAL  122880

#define ROWS    128
#define HSTRIDE 264         // h row stride in bf16 (528 B: 16B-aligned)
#define LOG2E   1.44269504f
#define LN2     0.69314718f
#define SPCONST 0.7806568f      // log(exp(1-1e-4)-1) * log2e
#define ZSENT  (-0.00015680f)   // raw-z sentinel whose softplus-chain -> d = 1

__global__ void prep_kernel(const float* __restrict__ W0,
                            const float* __restrict__ W1,
                            const float* __restrict__ Wout,
                            const float* __restrict__ bout,
                            __bf16* __restrict__ sw)
{
  int i = blockIdx.x * 256 + threadIdx.x;
  if (i >= SW_TOTAL + 192) return;
  if (i >= SW_TOTAL){                      // bout'[192] remap (float, *log2e)
    int np = i - SW_TOTAL;
    int t = np / 24, p = np % 24;
    float* boutp = (float*)(sw + SW_TOTAL);
    boutp[np] = (p < 23) ? bout[t*23 + p] * LOG2E : 0.f;
    return;
  }
  const float* src; int K, N, NT, li;
  bool wo = false;
  if (i < SW_W1_OFF)      { src = W0;   K = 8;   N = 256; NT = 16; li = i; }
  else if (i < SW_WO_OFF) { src = W1;   K = 256; N = 256; NT = 16; li = i - SW_W1_OFF; }
  else { src = Wout; K = 256; N = 184; NT = 12; li = i - SW_WO_OFF; wo = true; }
  int j    = li & 7;
  int l    = (li >> 3) & 63;
  int rest = li >> 9;
  int nt   = rest % NT;
  int kb   = rest / NT;
  int k = kb * 32 + ((l >> 4) << 3) + j;
  int n = nt * 16 + (l & 15);
  float v;
  if (wo){
    int t = n / 24, p = n % 24;            // n is padded col n' in 0..191
    v = (p < 23 && k < K) ? Wout[k*184 + t*23 + p] * LOG2E : 0.f;
  } else {
    v = (k < K && n < N) ? src[k * N + n] : 0.f;
  }
  sw[i] = (__bf16)v;
}

__device__ __forceinline__ bf16x4v relu_cvt(f32x4 s){
  const f32x4 z = {0.f, 0.f, 0.f, 0.f};
  s = __builtin_elementwise_max(s, z);
  return __builtin_convertvector(s, bf16x4v);   // v_cvt_pk_bf16_f32 x2
}

__device__ __forceinline__ f32x4 bias4(const float* p){
  float4 bb = *(const float4*)p;
  f32x4 c; c[0]=bb.x; c[1]=bb.y; c[2]=bb.z; c[3]=bb.w;
  return c;
}

__global__ __launch_bounds__(1024, 8)
void fused_kernel(const float* __restrict__ x,
                  const float* __restrict__ b0v,
                  const float* __restrict__ b1v,
                  const __bf16* __restrict__ sw,
                  float* __restrict__ out,
                  int nrows)
{
  // ONE aliased buffer: h1 -> h2 (in place) -> raw. 128 x 264 bf16 = 66 KB.
  __shared__ __align__(16) unsigned char smem[ROWS * HSTRIDE * 2];
  __bf16* hbuf = (__bf16*)smem;
  __bf16* rawb = hbuf;

  const int tid  = threadIdx.x;
  const int wave = tid >> 6;       // 0..15
  const int lane = tid & 63;
  const int quad = lane >> 4;
  const int l16  = lane & 15;
  const int row0 = blockIdx.x * ROWS;

  const __bf16* swW1 = sw + SW_W1_OFF;
  const __bf16* swWo = sw + SW_WO_OFF;
  const float* boutp = (const float*)(sw + SW_TOTAL);

  // ---- GEMM1 (16x16x32 transposed): h1[b][m] = relu(W0'^T x2 + b0)
  // wave = m-tile (16 waves, dup-free weights); loops all 8 batch tiles.
  {
    const int mt = wave;
    bf16x8 a = *(const bf16x8*)(sw + (mt*64 + lane)*8);
    f32x4 ci = bias4(b0v + mt*16 + quad*4);
    #pragma unroll
    for (int bt = 0; bt < 8; bt++){
      bf16x8 b = {};                       // k=quad*8+j; only quad 0 (k<8) real
      if (quad == 0){
        const float* xp = x + (long)(row0 + bt*16 + l16)*16 + 8;
        float4 u = *(const float4*)xp;
        float4 v = *(const float4*)(xp + 4);
        f32x8 xf; xf[0]=u.x; xf[1]=u.y; xf[2]=u.z; xf[3]=u.w;
                  xf[4]=v.x; xf[5]=v.y; xf[6]=v.z; xf[7]=v.w;
        b = __builtin_convertvector(xf, bf16x8);
      }
      f32x4 acc = MFMA16(a, b, ci);
      *(bf16x4v*)(hbuf + (bt*16 + l16)*HSTRIDE + mt*16 + quad*4) = relu_cvt(acc);
    }
  }
  __syncthreads();

  // ---- GEMM2 (16x16x32 transposed): h2[b][m] = relu(W1'^T h1 + b1)
  // wave = (mp: 8 m-pairs) x (bh: 2 batch-quads); weight dup x2 only.
  {
    const int mp = wave >> 1;
    const int bh = wave & 1;
    f32x4 acc[2][4];                       // [mi][bi]
    #pragma unroll
    for (int mi = 0; mi < 2; mi++){
      f32x4 ci = bias4(b1v + (mp*2 + mi)*16 + quad*4);
      #pragma unroll
      for (int bi = 0; bi < 4; bi++) acc[mi][bi] = ci;
    }
    #pragma unroll
    for (int kb = 0; kb < 8; kb++){
      bf16x8 hf[4];
      #pragma unroll
      for (int bi = 0; bi < 4; bi++)
        hf[bi] = *(const bf16x8*)(hbuf + ((bh*4+bi)*16 + l16)*HSTRIDE + kb*32 + quad*8);
      #pragma unroll
      for (int mi = 0; mi < 2; mi++){
        bf16x8 a = *(const bf16x8*)(swW1 + ((kb*16 + mp*2 + mi)*64 + lane)*8);
        #pragma unroll
        for (int bi = 0; bi < 4; bi++)
          acc[mi][bi] = MFMA16(a, hf[bi], acc[mi][bi]);
      }
    }
    __syncthreads();
    #pragma unroll
    for (int mi = 0; mi < 2; mi++)
      #pragma unroll
      for (int bi = 0; bi < 4; bi++)
        *(bf16x4v*)(hbuf + ((bh*4+bi)*16 + l16)*HSTRIDE + (mp*2+mi)*16 + quad*4) =
            relu_cvt(acc[mi][bi]);
  }
  __syncthreads();

  // ---- GEMM3 (16x16x32, 192 padded cols): raw2[b][n'] = Wout'^T h2 + bout'
  // wave = (nc: 4 groups of 3 n'-tiles) x (bq: 4 batch-pairs of 2 tiles)
  {
    const int nc = wave & 3;
    const int bq = wave >> 2;
    f32x4 acc[2][3];                       // [bt][mi]
    #pragma unroll
    for (int mi = 0; mi < 3; mi++){
      f32x4 ci = bias4(boutp + (nc*3+mi)*16 + quad*4);
      #pragma unroll
      for (int bt = 0; bt < 2; bt++) acc[bt][mi] = ci;
    }
    #pragma unroll
    for (int kb = 0; kb < 8; kb++){
      bf16x8 hf[2];
      #pragma unroll
      for (int bt = 0; bt < 2; bt++)
        hf[bt] = *(const bf16x8*)(hbuf + ((bq*2+bt)*16 + l16)*HSTRIDE + kb*32 + quad*8);
      #pragma unroll
      for (int mi = 0; mi < 3; mi++){
        bf16x8 a = *(const bf16x8*)(swWo + ((kb*12 + nc*3 + mi)*64 + lane)*8);
        #pragma unroll
        for (int bt = 0; bt < 2; bt++)
          acc[bt][mi] = MFMA16(a, hf[bt], acc[bt][mi]);
      }
    }
    __syncthreads();
    #pragma unroll
    for (int mi = 0; mi < 3; mi++){
      int mt = nc*3 + mi;
      #pragma unroll
      for (int bt = 0; bt < 2; bt++){
        int row = (bq*2+bt)*16 + l16;
        *(bf16x4v*)(rawb + row*HSTRIDE + mt*16 + quad*4) =
            __builtin_convertvector(acc[bt][mi], bf16x4v);
      }
    }
  }
  __syncthreads();

  // ---- RQ spline epilogue: 1024 tasks, 1/thread; FULL 64-B out-line write
  float ld;
  {
    int row = tid >> 3;                    // 0..127
    int t   = tid & 7;
    long gr = row0 + row;
    float xv = x[gr*16 + t];
    float xpass = x[gr*16 + 8 + t];        // passthrough half of the line

    const __bf16* rr = rawb + row*HSTRIDE + t*24;   // 48B slots, b128-aligned
    bf16x8 v0 = *(const bf16x8*)(rr);
    bf16x8 v1 = *(const bf16x8*)(rr + 8);
    bf16x8 v2 = *(const bf16x8*)(rr + 16);

    // raw2 already in log2-units: 2^raw2 = e^raw exactly
    f32x2 ewh[8];
    f32x2 sum = {0.f, 0.f};
    #pragma unroll
    for (int i=0;i<8;i++){
      f32x2 e;
      e[0] = __builtin_amdgcn_exp2f((float)v0[i]);
      e[1] = __builtin_amdgcn_exp2f((float)v1[i]);
      ewh[i] = e; sum += e;
    }
    f32x2 scale;
    scale[0] = 1.9984f * __builtin_amdgcn_rcpf(sum[0]);
    scale[1] = 1.9984f * __builtin_amdgcn_rcpf(sum[1]);
    const f32x2 off2 = {2e-4f, 2e-4f};

    bool msk = (xv <= -0.999f) || (xv >= 0.999f);
    float xin = msk ? 0.f : xv;

    // packed scan; sentinel-select raw z for the two needed derivatives
    f32x2 whi = ewh[0]*scale + off2;
    f32x2 ec; ec[0] = -1.f + whi[0]; ec[1] = -1.f + whi[1];
    f32x2 xyk = {-1.f, -1.f};
    f32x2 whk = whi;
    float zk = ZSENT, zk1 = (float)v2[0];
    #pragma unroll
    for (int i=1;i<8;i++){
      whi = ewh[i]*scale + off2;
      bool le = (ec[0] <= xin);
      xyk = le ? ec : xyk;
      whk = le ? whi : whk;
      zk  = le ? (float)v2[i-1] : zk;
      zk1 = le ? ((i==7) ? ZSENT : (float)v2[i]) : zk1;
      ec += whi;
    }

    // softplus (base-2) only for the two selected derivatives
    float za = zk + SPCONST, zb = zk1 + SPCONST;
    float dk  = (fmaxf(za,0.f) + __builtin_amdgcn_logf(1.f + __builtin_amdgcn_exp2f(-fabsf(za))))*LN2 + 1e-4f;
    float dk1 = (fmaxf(zb,0.f) + __builtin_amdgcn_logf(1.f + __builtin_amdgcn_exp2f(-fabsf(zb))))*LN2 + 1e-4f;

    float rwk = __builtin_amdgcn_rcpf(whk[0]);
    float sk  = whk[1] * rwk;
    float eps = (xin - xyk[0]) * rwk;
    float om  = 1.f - eps;
    float et  = eps * om;
    float e2  = eps * eps;
    float beta  = sk + (dk1 + dk - 2.f*sk) * et;
    float rb    = __builtin_amdgcn_rcpf(beta);
    float alpha = whk[1] * (sk*e2 + dk*et);
    float yv  = msk ? xv : (xyk[1] + alpha * rb);
    float num = dk1*e2 + 2.f*sk*et + dk*om*om;
    float ldv = msk ? 0.f : __builtin_amdgcn_logf(sk*sk*num*rb*rb) * LN2;

    out[gr*16 + t]     = yv;               // bytes 0..31 of the line
    out[gr*16 + 8 + t] = xpass;            // bytes 32..63: adjacent store,
    ld = ldv;                              // L2 merges -> one HBM write
  }

  // per-row logdet: 8 t-lanes are adjacent -> 3-step shfl_xor reduction
  float s0 = ld;
  #pragma unroll
  for (int m = 1; m < 8; m <<= 1)
    s0 += __shfl_xor(s0, m);
  if ((lane & 7) == 0)
    out[(long)nrows*16 + row0 + (tid >> 3)] = s0;
}

extern "C" void kernel_launch(void* const* d_in, const int* in_sizes, int n_in,
                              void* d_out, int out_size, void* d_ws, size_t ws_size,
                              hipStream_t stream)
{
  const float* x    = (const float*)d_in[0];
  const float* W0   = (const float*)d_in[1];
  const float* b0   = (const float*)d_in[2];
  const float* W1   = (const float*)d_in[3];
  const float* b1   = (const float*)d_in[4];
  const float* Wout = (const float*)d_in[5];
  const float* bout = (const float*)d_in[6];
  float* out = (float*)d_out;
  __bf16* sw = (__bf16*)d_ws;

  int nrows = in_sizes[0] / 16;          // 524288
  int ntiles = nrows / ROWS;             // 4096

  prep_kernel<<<(SW_TOTAL + 192 + 255)/256, 256, 0, stream>>>(W0, W1, Wout, bout, sw);
  fused_kernel<<<ntiles, 1024, 0, stream>>>(x, b0, b1, sw, out, nrows);
}

// Round 4
// 242.319 us; speedup vs baseline: 1.1516x; 1.1516x over previous
//
#include <hip/hip_runtime.h>
#include <hip/hip_bf16.h>

// CouplingSplineLayer fused kernel for MI355X (gfx950), round 12.
// R12 = R8 skeleton (the 162 us champion: 512 thr, ROWS=128, 2 blocks/CU,
// split passthrough stores -- proven 35 MB WRITE_SIZE) with two riders:
//  * G2/G3 wave remap (mg:2 x bg:4): h-fragment LDS reads halve (dup 4->2);
//    weight A-frags shift to the L1/global path (all waves stream the same
//    sequence -> L1 broadcast). LDS pipe was ~50% of wall incl. 61k
//    conflict-cycles/CU; this halves its instruction count.
//  * bias folded into the MFMA C-operand (proven absmax-identical R9-R11).
// Everything else byte-identical to R8 (G1, epilogue, prep, layouts).

typedef __bf16 bf16x8 __attribute__((ext_vector_type(8)));
typedef __bf16 bf16x4v __attribute__((ext_vector_type(4)));
typedef float  f32x8 __attribute__((ext_vector_type(8)));
typedef float  f32x4 __attribute__((ext_vector_type(4)));
typedef float  f32x2 __attribute__((ext_vector_type(2)));

#define MFMA16(a,b,c) __builtin_amdgcn_mfma_f32_16x16x32_bf16((a),(b),(c),0,0,0)

#define SW_W1_OFF 8192      // W0: 1 kb * 16 tiles * 512
#define SW_WO_OFF 73728     // W1: 8 kb * 16 tiles * 512
#define SW_TOTAL  122880    // Wout': 8 kb * 12 tiles * 512 (192 padded cols)
// float bout'[192] lives at d_ws + SW_TOTAL*2 bytes

#define ROWS    128
#define HSTRIDE 264         // h row stride in bf16 (528 B: 16B-aligned)
#define LOG2E   1.44269504f
#define LN2     0.69314718f
#define SPCONST 0.7806568f      // log(exp(1-1e-4)-1) * log2e
#define ZSENT  (-0.00015680f)   // raw-z sentinel whose softplus-chain -> d = 1

__global__ void prep_kernel(const float* __restrict__ W0,
                            const float* __restrict__ W1,
                            const float* __restrict__ Wout,
                            const float* __restrict__ bout,
                            __bf16* __restrict__ sw)
{
  int i = blockIdx.x * 256 + threadIdx.x;
  if (i >= SW_TOTAL + 192) return;
  if (i >= SW_TOTAL){                      // bout'[192] remap (float, *log2e)
    int np = i - SW_TOTAL;
    int t = np / 24, p = np % 24;
    float* boutp = (float*)(sw + SW_TOTAL);
    boutp[np] = (p < 23) ? bout[t*23 + p] * LOG2E : 0.f;
    return;
  }
  const float* src; int K, N, NT, li;
  bool wo = false;
  if (i < SW_W1_OFF)      { src = W0;   K = 8;   N = 256; NT = 16; li = i; }
  else if (i < SW_WO_OFF) { src = W1;   K = 256; N = 256; NT = 16; li = i - SW_W1_OFF; }
  else { src = Wout; K = 256; N = 184; NT = 12; li = i - SW_WO_OFF; wo = true; }
  int j    = li & 7;
  int l    = (li >> 3) & 63;
  int rest = li >> 9;
  int nt   = rest % NT;
  int kb   = rest / NT;
  int k = kb * 32 + ((l >> 4) << 3) + j;
  int n = nt * 16 + (l & 15);
  float v;
  if (wo){
    int t = n / 24, p = n % 24;            // n is padded col n' in 0..191
    v = (p < 23 && k < K) ? Wout[k*184 + t*23 + p] * LOG2E : 0.f;
  } else {
    v = (k < K && n < N) ? src[k * N + n] : 0.f;
  }
  sw[i] = (__bf16)v;
}

__device__ __forceinline__ bf16x4v relu_cvt(f32x4 s){
  const f32x4 z = {0.f, 0.f, 0.f, 0.f};
  s = __builtin_elementwise_max(s, z);
  return __builtin_convertvector(s, bf16x4v);   // v_cvt_pk_bf16_f32 x2
}

__device__ __forceinline__ f32x4 bias4(const float* p){
  float4 bb = *(const float4*)p;
  f32x4 c; c[0]=bb.x; c[1]=bb.y; c[2]=bb.z; c[3]=bb.w;
  return c;
}

__global__ __launch_bounds__(512, 4)
void fused_kernel(const float* __restrict__ x,
                  const float* __restrict__ b0v,
                  const float* __restrict__ b1v,
                  const __bf16* __restrict__ sw,
                  float* __restrict__ out,
                  int nrows)
{
  // ONE aliased buffer: h1 -> h2 (in place) -> raw. 128 x 264 bf16 = 66 KB.
  __shared__ __align__(16) unsigned char smem[ROWS * HSTRIDE * 2];
  __bf16* hbuf = (__bf16*)smem;
  __bf16* rawb = hbuf;

  const int tid  = threadIdx.x;
  const int wave = tid >> 6;
  const int lane = tid & 63;
  const int quad = lane >> 4;
  const int l16  = lane & 15;
  const int row0 = blockIdx.x * ROWS;

  const __bf16* swW1 = sw + SW_W1_OFF;
  const __bf16* swWo = sw + SW_WO_OFF;
  const float* boutp = (const float*)(sw + SW_TOTAL);

  // ---- x2 passthrough: 2 float4 per row on 256 threads (independent)
  if (tid < 2*ROWS){
    int r = tid >> 1, hf = tid & 1;
    long g = (long)row0 + r;
    *(float4*)(out + g*16 + 8 + hf*4) = *(const float4*)(x + g*16 + 8 + hf*4);
  }

  const int mq = wave >> 1;   // m-quarter (4 m-tiles) for G1
  const int nh = wave & 1;    // batch-half (4 batch-tiles) for G1

  // ---- GEMM1 (transposed): h1[b][m] = relu(W0'^T x2 + b0), bias in C
  {
    bf16x8 bfr[4];
    #pragma unroll
    for (int nt = 0; nt < 4; nt++){
      bf16x8 b = {};                       // k=quad*8+j; only quad 0 (k<8) real
      if (quad == 0){
        const float* xp = x + (long)(row0 + (nh*4 + nt)*16 + l16)*16 + 8;
        float4 u = *(const float4*)xp;
        float4 v = *(const float4*)(xp + 4);
        f32x8 xf; xf[0]=u.x; xf[1]=u.y; xf[2]=u.z; xf[3]=u.w;
                  xf[4]=v.x; xf[5]=v.y; xf[6]=v.z; xf[7]=v.w;
        b = __builtin_convertvector(xf, bf16x8);
      }
      bfr[nt] = b;
    }
    #pragma unroll
    for (int mi = 0; mi < 4; mi++){
      int mt = mq*4 + mi;
      bf16x8 a = *(const bf16x8*)(sw + (mt*64 + lane)*8);
      f32x4 ci = bias4(b0v + mt*16 + quad*4);
      #pragma unroll
      for (int nt = 0; nt < 4; nt++){
        f32x4 acc = MFMA16(a, bfr[nt], ci);
        *(bf16x4v*)(hbuf + ((nh*4+nt)*16 + l16)*HSTRIDE + mt*16 + quad*4) = relu_cvt(acc);
      }
    }
  }
  __syncthreads();

  // ---- GEMM2 (transposed): h2[b][m] = relu(W1'^T h1 + b1), bias in C
  // wave = (mg: 2 m-groups of 8 mt) x (bg: 4 batch-groups of 2 bt).
  // h-fragment LDS reads: dup 2x (was 4x); W1 frags via L1 (same stream
  // across waves).
  {
    const int mg = wave >> 2;
    const int bg = wave & 3;
    f32x4 acc[8][2];                       // [mi][bi]
    #pragma unroll
    for (int mi = 0; mi < 8; mi++){
      f32x4 ci = bias4(b1v + (mg*8 + mi)*16 + quad*4);
      acc[mi][0] = ci; acc[mi][1] = ci;
    }
    #pragma unroll
    for (int kb = 0; kb < 8; kb++){
      bf16x8 hf[2];
      #pragma unroll
      for (int bi = 0; bi < 2; bi++)
        hf[bi] = *(const bf16x8*)(hbuf + ((bg*2+bi)*16 + l16)*HSTRIDE + kb*32 + quad*8);
      #pragma unroll
      for (int mi = 0; mi < 8; mi++){
        bf16x8 a = *(const bf16x8*)(swW1 + ((kb*16 + mg*8 + mi)*64 + lane)*8);
        acc[mi][0] = MFMA16(a, hf[0], acc[mi][0]);
        acc[mi][1] = MFMA16(a, hf[1], acc[mi][1]);
      }
    }
    __syncthreads();
    #pragma unroll
    for (int mi = 0; mi < 8; mi++)
      #pragma unroll
      for (int bi = 0; bi < 2; bi++)
        *(bf16x4v*)(hbuf + ((bg*2+bi)*16 + l16)*HSTRIDE + (mg*8+mi)*16 + quad*4) =
            relu_cvt(acc[mi][bi]);
  }
  __syncthreads();

  // ---- GEMM3 (TRANSPOSED, 192 padded cols): raw2[b][n'] = Wout'^T h2 + bout'
  // wave = (ng: 2 n-groups of 6 nt) x (bg: 4 batch-groups of 2 bt).
  {
    const int ng = wave >> 2;
    const int bg = wave & 3;
    f32x4 acc[6][2];                       // [mi][bi]
    #pragma unroll
    for (int mi = 0; mi < 6; mi++){
      f32x4 ci = bias4(boutp + (ng*6+mi)*16 + quad*4);
      acc[mi][0] = ci; acc[mi][1] = ci;
    }
    #pragma unroll
    for (int kb = 0; kb < 8; kb++){
      bf16x8 hf[2];
      #pragma unroll
      for (int bi = 0; bi < 2; bi++)
        hf[bi] = *(const bf16x8*)(hbuf + ((bg*2+bi)*16 + l16)*HSTRIDE + kb*32 + quad*8);
      #pragma unroll
      for (int mi = 0; mi < 6; mi++){
        bf16x8 a = *(const bf16x8*)(swWo + ((kb*12 + ng*6 + mi)*64 + lane)*8);
        acc[mi][0] = MFMA16(a, hf[0], acc[mi][0]);
        acc[mi][1] = MFMA16(a, hf[1], acc[mi][1]);
      }
    }
    __syncthreads();
    #pragma unroll
    for (int mi = 0; mi < 6; mi++){
      int mt = ng*6 + mi;
      #pragma unroll
      for (int bi = 0; bi < 2; bi++){
        int row = (bg*2+bi)*16 + l16;
        *(bf16x4v*)(rawb + row*HSTRIDE + mt*16 + quad*4) =
            __builtin_convertvector(acc[mi][bi], bf16x4v);
      }
    }
  }
  __syncthreads();

  // ---- RQ spline epilogue: 1024 tasks, 2/thread; ldet via shfl_xor
  float ldv[2];
  #pragma unroll
  for (int pp = 0; pp < 2; pp++){
    int p   = tid + pp*512;
    int row = p >> 3;
    int t   = p & 7;
    long gr = row0 + row;
    float xv = x[gr*16 + t];

    const __bf16* rr = rawb + row*HSTRIDE + t*24;   // 48B slots, b128-aligned
    bf16x8 v0 = *(const bf16x8*)(rr);
    bf16x8 v1 = *(const bf16x8*)(rr + 8);
    bf16x8 v2 = *(const bf16x8*)(rr + 16);

    // raw2 already in log2-units: 2^raw2 = e^raw exactly
    f32x2 ewh[8];
    f32x2 sum = {0.f, 0.f};
    #pragma unroll
    for (int i=0;i<8;i++){
      f32x2 e;
      e[0] = __builtin_amdgcn_exp2f((float)v0[i]);
      e[1] = __builtin_amdgcn_exp2f((float)v1[i]);
      ewh[i] = e; sum += e;
    }
    f32x2 scale;
    scale[0] = 1.9984f * __builtin_amdgcn_rcpf(sum[0]);
    scale[1] = 1.9984f * __builtin_amdgcn_rcpf(sum[1]);
    const f32x2 off2 = {2e-4f, 2e-4f};

    bool msk = (xv <= -0.999f) || (xv >= 0.999f);
    float xin = msk ? 0.f : xv;

    // packed scan; sentinel-select raw z for the two needed derivatives
    f32x2 whi = ewh[0]*scale + off2;
    f32x2 ec; ec[0] = -1.f + whi[0]; ec[1] = -1.f + whi[1];
    f32x2 xyk = {-1.f, -1.f};
    f32x2 whk = whi;
    float zk = ZSENT, zk1 = (float)v2[0];
    #pragma unroll
    for (int i=1;i<8;i++){
      whi = ewh[i]*scale + off2;
      bool le = (ec[0] <= xin);
      xyk = le ? ec : xyk;
      whk = le ? whi : whk;
      zk  = le ? (float)v2[i-1] : zk;
      zk1 = le ? ((i==7) ? ZSENT : (float)v2[i]) : zk1;
      ec += whi;
    }

    // softplus (base-2) only for the two selected derivatives
    float za = zk + SPCONST, zb = zk1 + SPCONST;
    float dk  = (fmaxf(za,0.f) + __builtin_amdgcn_logf(1.f + __builtin_amdgcn_exp2f(-fabsf(za))))*LN2 + 1e-4f;
    float dk1 = (fmaxf(zb,0.f) + __builtin_amdgcn_logf(1.f + __builtin_amdgcn_exp2f(-fabsf(zb))))*LN2 + 1e-4f;

    float rwk = __builtin_amdgcn_rcpf(whk[0]);
    float sk  = whk[1] * rwk;
    float eps = (xin - xyk[0]) * rwk;
    float om  = 1.f - eps;
    float et  = eps * om;
    float e2  = eps * eps;
    float beta  = sk + (dk1 + dk - 2.f*sk) * et;
    float rb    = __builtin_amdgcn_rcpf(beta);
    float alpha = whk[1] * (sk*e2 + dk*et);
    float yv  = msk ? xv : (xyk[1] + alpha * rb);
    float num = dk1*e2 + 2.f*sk*et + dk*om*om;
    float ld  = msk ? 0.f : __builtin_amdgcn_logf(sk*sk*num*rb*rb) * LN2;

    out[gr*16 + t] = yv;
    ldv[pp] = ld;
  }

  // per-row logdet: 8 t-lanes are adjacent -> 3-step shfl_xor reduction
  float s0 = ldv[0], s1 = ldv[1];
  #pragma unroll
  for (int m = 1; m < 8; m <<= 1){
    s0 += __shfl_xor(s0, m);
    s1 += __shfl_xor(s1, m);
  }
  if ((lane & 7) == 0){
    int r = tid >> 3;                    // 0..63
    out[(long)nrows*16 + row0 + r]      = s0;
    out[(long)nrows*16 + row0 + r + 64] = s1;
  }
}

extern "C" void kernel_launch(void* const* d_in, const int* in_sizes, int n_in,
                              void* d_out, int out_size, void* d_ws, size_t ws_size,
                              hipStream_t stream)
{
  const float* x    = (const float*)d_in[0];
  const float* b0   = (const float*)d_in[2];
  const float* W0   = (const float*)d_in[1];
  const float* W1   = (const float*)d_in[3];
  const float* b1   = (const float*)d_in[4];
  const float* Wout = (const float*)d_in[5];
  const float* bout = (const float*)d_in[6];
  float* out = (float*)d_out;
  __bf16* sw = (__bf16*)d_ws;

  int nrows = in_sizes[0] / 16;          // 524288
  int ntiles = nrows / ROWS;             // 4096

  prep_kernel<<<(SW_TOTAL + 192 + 255)/256, 256, 0, stream>>>(W0, W1, Wout, bout, sw);
  fused_kernel<<<ntiles, 512, 0, stream>>>(x, b0, b1, sw, out, nrows);
}